// Round 2
// 265.304 us; speedup vs baseline: 1.0436x; 1.0436x over previous
//
#include <hip/hip_runtime.h>

#define DIM 768
#define NHEADS 12
#define HDIM 64
#define BB 16
#define NN 784
#define M_TOTAL (BB * NN)   // 12544

typedef __attribute__((ext_vector_type(8))) _Float16 f16x8;
typedef __attribute__((ext_vector_type(4))) float f32x4;
typedef __attribute__((ext_vector_type(16))) float f32x16;

// ---- async global->LDS, 16B per lane ------------------------------------
typedef __attribute__((address_space(3))) unsigned int lds_uint;
typedef __attribute__((address_space(1))) const unsigned int g_uint;
__device__ inline void gload_lds16(const void* g, void* l) {
    __builtin_amdgcn_global_load_lds((g_uint*)(uintptr_t)g,
                                     (lds_uint*)(uintptr_t)l, 16, 0, 0);
}

// ---------------------------------------------------------------------------
// f32 -> f16 elementwise (x8 per thread)
// ---------------------------------------------------------------------------
__global__ __launch_bounds__(256) void cvt_f16_kernel(
    const float* __restrict__ in, _Float16* __restrict__ out, int n)
{
    int i = (blockIdx.x * 256 + threadIdx.x) * 8;
    if (i >= n) return;
    float4 a = *(const float4*)&in[i];
    float4 b = *(const float4*)&in[i + 4];
    union { _Float16 h[8]; uint4 v; } o;
    o.h[0] = (_Float16)a.x; o.h[1] = (_Float16)a.y;
    o.h[2] = (_Float16)a.z; o.h[3] = (_Float16)a.w;
    o.h[4] = (_Float16)b.x; o.h[5] = (_Float16)b.y;
    o.h[6] = (_Float16)b.z; o.h[7] = (_Float16)b.w;
    *(uint4*)&out[i] = o.v;
}

// ---------------------------------------------------------------------------
// W[K][N] f32 -> WT[N][K] f16 (32x32 LDS tile transpose)
// ---------------------------------------------------------------------------
__global__ __launch_bounds__(256) void transpose_f16_kernel(
    const float* __restrict__ W, _Float16* __restrict__ T, int K, int N)
{
    __shared__ float t[32][33];
    const int n0 = blockIdx.x * 32, k0 = blockIdx.y * 32;
    const int r = threadIdx.x >> 3, c4 = (threadIdx.x & 7) * 4;
    float4 v = *(const float4*)&W[(size_t)(k0 + r) * N + n0 + c4];
    t[r][c4 + 0] = v.x; t[r][c4 + 1] = v.y;
    t[r][c4 + 2] = v.z; t[r][c4 + 3] = v.w;
    __syncthreads();
    union { _Float16 h[4]; ushort4 v4; } o;
#pragma unroll
    for (int i = 0; i < 4; ++i) o.h[i] = (_Float16)t[c4 + i][r];
    *(ushort4*)&T[(size_t)(n0 + r) * K + k0 + c4] = o.v4;
}

// ---------------------------------------------------------------------------
// f16 MFMA GEMM, 32x32x16 variant: C[M,N] = A[M,K] @ B^T[N,K] + bias[N]
// (unchanged)
// ---------------------------------------------------------------------------
template <int OUT_F16>
__global__ __launch_bounds__(256) void gemm_f16_kernel(
    const _Float16* __restrict__ A, const _Float16* __restrict__ B,
    const float* __restrict__ bias, void* __restrict__ Cout,
    int M, int N, int K)
{
    __shared__ _Float16 sA[128 * 64];   // [m][k], swizzled chunks
    __shared__ _Float16 sB[128 * 64];   // [n][k], swizzled chunks

    const int tid  = threadIdx.x;
    const int wave = tid >> 6;
    const int lane = tid & 63;
    const int gm = blockIdx.y * 128;
    const int gn = blockIdx.x * 128;
    const int wm = (wave & 1) * 64;
    const int wn = (wave >> 1) * 64;
    const int l31 = lane & 31;
    const int hi  = lane >> 5;          // 0/1: k sub-chunk

    const int srow = lane >> 3;                              // 0..7
    const int scol = (((lane & 7) ^ (srow & 7)) * 8);        // swizzled f16 col

    f32x16 acc[2][2] = {};

    for (int k0 = 0; k0 < K; k0 += 64) {
        __syncthreads();
#pragma unroll
        for (int i = 0; i < 4; ++i) {
            const int rbase = wave * 32 + i * 8;
            gload_lds16(A + (size_t)(gm + rbase + srow) * K + k0 + scol,
                        &sA[rbase * 64]);
            gload_lds16(B + (size_t)(gn + rbase + srow) * K + k0 + scol,
                        &sB[rbase * 64]);
        }
        __syncthreads();

#pragma unroll
        for (int kk = 0; kk < 4; ++kk) {
            const int c = kk * 2 + hi;          // logical 16B chunk
            const int sw = (c ^ (l31 & 7)) * 8; // physical f16 offset
            f16x8 a[2], bf[2];
#pragma unroll
            for (int mt = 0; mt < 2; ++mt)
                a[mt] = *(const f16x8*)&sA[(wm + mt * 32 + l31) * 64 + sw];
#pragma unroll
            for (int nt = 0; nt < 2; ++nt)
                bf[nt] = *(const f16x8*)&sB[(wn + nt * 32 + l31) * 64 + sw];
#pragma unroll
            for (int mt = 0; mt < 2; ++mt)
#pragma unroll
                for (int nt = 0; nt < 2; ++nt)
                    acc[mt][nt] = __builtin_amdgcn_mfma_f32_32x32x16_f16(
                        a[mt], bf[nt], acc[mt][nt], 0, 0, 0);
        }
    }

#pragma unroll
    for (int nt = 0; nt < 2; ++nt) {
        const int col = gn + wn + nt * 32 + l31;
        const float bv = bias[col];
#pragma unroll
        for (int mt = 0; mt < 2; ++mt) {
            f32x16 v = acc[mt][nt];
#pragma unroll
            for (int reg = 0; reg < 16; ++reg) {
                const int row = gm + wm + mt * 32 + (reg & 3) + 8 * (reg >> 2) + 4 * hi;
                const float o = v[reg] + bv;
                if (OUT_F16)
                    ((_Float16*)Cout)[(size_t)row * N + col] = (_Float16)o;
                else
                    ((float*)Cout)[(size_t)row * N + col] = o;
            }
        }
    }
}

// ---------------------------------------------------------------------------
// f16 MFMA flash attention, no-max softmax, P kept in registers.
// QK^T computed operand-swapped: S^T = mfma(K_frag, Q_frag) -> each lane
// (quad, l16) holds P[q=l16][j = nt*16 + quad*4 + r] in s[nt][r].
// NO cross-lane redistribution: instead V is staged into Vt with a permuted
// column  p = (j>>5)*32 + ((j>>2)&3)*8 + ((j>>4)&1)*4 + (j&3)
// so the post-exp2 registers feed the PV A-fragment directly:
//   pa(c) = {pk[2c][0], pk[2c][1], pk[2c+1][0], pk[2c+1][1]}
//   element e of lane(quad): j = c*32 + (e>>2)*16 + quad*4 + (e&3)  == pi(p).
// Removes the entire P LDS round-trip (16 b16 writes + 2 b128 reads + its
// 4-way bank conflicts) and all lane-crossing ops. LDS 27648 -> 18432 B.
// ---------------------------------------------------------------------------
#define LOG2E_8 0.18033688f  // 0.125 * log2(e)

#define ATTN_TILE(J0, TAIL)                                                    \
  {                                                                            \
    const int j0_ = (J0);                                                      \
    int jrowK = j0_ + sj;                                                      \
    if (TAIL && jrowK > NN - 1) jrowK = NN - 1;                                \
    const size_t kbase = (size_t)(b * NN + jrowK) * (3 * DIM) + DIM + h * HDIM;\
    uint4 k0v = *(const uint4*)&qkv[kbase + sg * 8];                           \
    uint4 k1v = *(const uint4*)&qkv[kbase + sg * 8 + 32];                      \
    int vr0 = j0_ + 2 * jj, vr1 = j0_ + 2 * jj + 1;                            \
    if (TAIL) { if (vr0 > NN - 1) vr0 = NN - 1; if (vr1 > NN - 1) vr1 = NN - 1; } \
    const size_t vb0 = (size_t)(b * NN + vr0) * (3 * DIM) + 2 * DIM + h * HDIM + dsub; \
    const size_t vb1 = (size_t)(b * NN + vr1) * (3 * DIM) + 2 * DIM + h * HDIM + dsub; \
    union { uint4 v; _Float16 h[8]; } va, vc;                                  \
    va.v = *(const uint4*)&qkv[vb0];                                           \
    vc.v = *(const uint4*)&qkv[vb1];                                           \
    __syncthreads();                                                           \
    *(uint4*)&Ks[sj][sg * 8]      = k0v;                                       \
    *(uint4*)&Ks[sj][sg * 8 + 32] = k1v;                                       \
    _Pragma("unroll")                                                          \
    for (int i = 0; i < 8; ++i) {                                              \
        union { _Float16 h[2]; unsigned int u; } t;                            \
        t.h[0] = va.h[i]; t.h[1] = vc.h[i];                                    \
        *(unsigned int*)&Vt[dsub + i][pcol] = t.u;                             \
    }                                                                          \
    __syncthreads();                                                           \
    f32x4 s[4] = {};                                                           \
    _Pragma("unroll")                                                          \
    for (int nt = 0; nt < 4; ++nt) {                                           \
        f16x8 kf0 = *(const f16x8*)&Ks[nt * 16 + l16][quad * 8];               \
        f16x8 kf1 = *(const f16x8*)&Ks[nt * 16 + l16][32 + quad * 8];          \
        s[nt] = __builtin_amdgcn_mfma_f32_16x16x32_f16(kf0, qfrag[0], s[nt], 0, 0, 0); \
        s[nt] = __builtin_amdgcn_mfma_f32_16x16x32_f16(kf1, qfrag[1], s[nt], 0, 0, 0); \
    }                                                                          \
    unsigned int pk[4][2];                                                     \
    _Pragma("unroll")                                                          \
    for (int nt = 0; nt < 4; ++nt) {                                           \
        float pv[4];                                                           \
        _Pragma("unroll")                                                      \
        for (int r = 0; r < 4; ++r) {                                          \
            float p = exp2f(s[nt][r]);                                         \
            if (TAIL && (j0_ + nt * 16) >= NN) p = 0.f;                        \
            lpart += p;                                                        \
            pv[r] = p;                                                         \
        }                                                                      \
        union { _Float16 h[2]; unsigned int u; } c0, c1;                       \
        c0.h[0] = (_Float16)pv[0]; c0.h[1] = (_Float16)pv[1];                  \
        c1.h[0] = (_Float16)pv[2]; c1.h[1] = (_Float16)pv[3];                  \
        pk[nt][0] = c0.u; pk[nt][1] = c1.u;                                    \
    }                                                                          \
    _Pragma("unroll")                                                          \
    for (int pc = 0; pc < 2; ++pc) {                                           \
        union { unsigned int u[4]; f16x8 v; } pa;                              \
        pa.u[0] = pk[2 * pc][0];     pa.u[1] = pk[2 * pc][1];                  \
        pa.u[2] = pk[2 * pc + 1][0]; pa.u[3] = pk[2 * pc + 1][1];              \
        _Pragma("unroll")                                                      \
        for (int dt = 0; dt < 4; ++dt) {                                       \
            f16x8 vf = *(const f16x8*)&Vt[dt * 16 + l16][pc * 32 + quad * 8];  \
            O[dt] = __builtin_amdgcn_mfma_f32_16x16x32_f16(pa.v, vf, O[dt], 0, 0, 0); \
        }                                                                      \
    }                                                                          \
  }

__global__ __launch_bounds__(256) void attn_f16_kernel(
    const _Float16* __restrict__ qkv, _Float16* __restrict__ oat)
{
    // XCD-aware remap: give each XCD whole (b,h) groups so the 13 q-tile
    // blocks sharing one K/V panel co-reside in one L2. 2496 = 8*24*13.
    const int L   = blockIdx.x + 13 * (blockIdx.y + NHEADS * blockIdx.z);
    const int xcd = L & 7, ixc = L >> 3;
    const int grp = xcd * 24 + ixc / 13;
    const int q0  = (ixc % 13) * 64;
    const int b   = grp / NHEADS;
    const int h   = grp % NHEADS;

    const int tid = threadIdx.x;
    const int wave = tid >> 6;
    const int lane = tid & 63;
    const int quad = lane >> 4;
    const int l16  = lane & 15;

    __shared__ _Float16 Ks[64][72];   // K tile [j][d]
    __shared__ _Float16 Vt[64][72];   // V^T    [d][p], p = permuted j

    // ---- Q B-frags, scaled by 0.125*log2e (exp2-domain softmax)
    f16x8 qfrag[2];
    {
        int qrow = q0 + wave * 16 + l16; if (qrow > NN - 1) qrow = NN - 1;
        size_t base = (size_t)(b * NN + qrow) * (3 * DIM) + h * HDIM;
        f16x8 q0v = *(const f16x8*)&qkv[base + quad * 8];
        f16x8 q1v = *(const f16x8*)&qkv[base + 32 + quad * 8];
        qfrag[0] = q0v * (_Float16)LOG2E_8;
        qfrag[1] = q1v * (_Float16)LOG2E_8;
    }

    // staging maps
    const int sj = lane;                         // K: row within j-tile
    const int sg = wave;                         // K: d-chunk (wave-uniform)
    const int jj   = lane & 31;                  // V: j pair index (j = 2*jj)
    const int dsub = sg * 16 + (lane >> 5) * 8;  // V: 8 d's
    // permuted column for V rows (2jj, 2jj+1):
    // p(j) = (j>>5)*32 + ((j>>2)&3)*8 + ((j>>4)&1)*4 + (j&3)
    const int pcol = ((jj >> 4) << 5) | (((jj >> 1) & 3) << 3)
                   | (((jj >> 3) & 1) << 2) | ((jj & 1) << 1);

    f32x4 O[4] = {};
    float lpart = 0.f;   // per-lane partial denominator for q = l16

    for (int jt = 0; jt < 12; ++jt) {
        ATTN_TILE(jt * 64, 0)
    }
    ATTN_TILE(768, 1)

    // ---- deferred l reduction: sum the 4 quads holding the same q = l16
    float t = lpart;
    t += __shfl_xor(t, 16);
    t += __shfl_xor(t, 32);
    // redistribute: output row layout has q_local = quad*4 + r
    float inv[4];
#pragma unroll
    for (int r = 0; r < 4; ++r)
        inv[r] = 1.0f / __shfl(t, quad * 4 + r, 16);

    // ---- epilogue
#pragma unroll
    for (int r = 0; r < 4; ++r) {
        const int q = q0 + wave * 16 + quad * 4 + r;
        if (q < NN) {
#pragma unroll
            for (int dt = 0; dt < 4; ++dt) {
                const size_t base = (size_t)(b * NN + q) * DIM + h * HDIM + dt * 16 + l16;
                oat[base] = (_Float16)(O[dt][r] * inv[r]);
            }
        }
    }
}

// ---------------------------------------------------------------------------
extern "C" void kernel_launch(void* const* d_in, const int* in_sizes, int n_in,
                              void* d_out, int out_size, void* d_ws, size_t ws_size,
                              hipStream_t stream) {
    const float* x    = (const float*)d_in[0];
    const float* Wqkv = (const float*)d_in[1];
    const float* bqkv = (const float*)d_in[2];
    const float* Wo   = (const float*)d_in[3];
    const float* bo   = (const float*)d_in[4];
    float* out = (float*)d_out;

    _Float16* qkv = (_Float16*)d_ws;                    // M x 2304
    _Float16* xh  = qkv + (size_t)M_TOTAL * 3 * DIM;    // M x 768
    _Float16* wqT = xh + (size_t)M_TOTAL * DIM;         // 2304 x 768
    _Float16* woT = wqT + (size_t)3 * DIM * DIM;        // 768 x 768
    _Float16* oat = xh;  // attn out reuses xh (x dead after GEMM1)

    {
        int n = M_TOTAL * DIM;
        cvt_f16_kernel<<<n / 8 / 256, 256, 0, stream>>>(x, xh, n);
    }
    transpose_f16_kernel<<<dim3((3 * DIM) / 32, DIM / 32), 256, 0, stream>>>(
        Wqkv, wqT, DIM, 3 * DIM);
    transpose_f16_kernel<<<dim3(DIM / 32, DIM / 32), 256, 0, stream>>>(
        Wo, woT, DIM, DIM);
    gemm_f16_kernel<1><<<dim3((3 * DIM) / 128, M_TOTAL / 128), 256, 0, stream>>>(
        xh, wqT, bqkv, qkv, M_TOTAL, 3 * DIM, DIM);
    attn_f16_kernel<<<dim3(13, NHEADS, BB), 256, 0, stream>>>(qkv, oat);
    gemm_f16_kernel<0><<<dim3(DIM / 128, M_TOTAL / 128), 256, 0, stream>>>(
        oat, woT, bo, out, M_TOTAL, DIM, DIM);
}